// Round 3
// baseline (191.748 us; speedup 1.0000x reference)
//
#include <hip/hip_runtime.h>

// ---------------------------------------------------------------------------
// QuantizedShaper: B=256, L=8192, DIM=256, NPAT=64, HIST=32, WIN=8, T=1024.
//
// R15: 4-patterns-per-lane scan (16 active lanes). Evidence R12/R13/R14:
// per-step cost ~= one cross-lane chain (~22-25 cyc per dependent cross-lane
// op; R13 with 2 chains/step was exactly 2x R14's 1 chain/step) + ~100 cyc
// fixed (VGPR=68 => compiler re-read U from LDS per step + lgkmcnt stall).
// Fixes, keeping R12's validated numerics bitwise per pattern:
//   - pattern p -> (lane p>>2, slot p&3): reduce = 2-level local fmax tree
//     + 4 row-confined DPP stages (xor1/2/4/8 within 16 lanes). 8 deps/step,
//     only 4 cross-lane (was 6 incl. permlanes).
//   - per-step U is ONE float4: 4-deep rotating register prefetch (static
//     indices, fully unrolled) issues the ds_read_b128 4 steps early.
//   - winners: 4 per-lane bitmasks (pure VALU); ballot/ffs extraction split
//     across the 3 fill waves one chunk behind, writing bytes to idx8[].
// Same expressions per pattern: vA = U[i+1]-C, vB = vA-1, e = (v == gmax);
// gmax is max of the same finite set (fmax exact, topology-independent).
// Garbage lanes >=16: row-confined DPP isolates them; extraction ballots
// masked with 0xFFFF.
// ---------------------------------------------------------------------------

constexpr int Bb = 256, Ll = 8192, DIMc = 256, NPAT = 64, HIST = 32, WINc = 8;
constexpr int Tt = Ll / WINc;   // 1024
constexpr int TC = 32;          // t-chunk
constexpr int NC = Tt / TC;     // 32 chunks
constexpr float CINV = 1.0f / 64.0f;

#define DPP_STAGE(m, ctrl, rmask)                                              \
  (m) = fmaxf((m), __int_as_float(__builtin_amdgcn_update_dpp(                 \
            __float_as_int(m), __float_as_int(m), (ctrl), (rmask), 0xF, false)))

#define DPP_ADDF(s, ctrl, rmask)                                               \
  do {                                                                         \
    int _si = __float_as_int(s);                                               \
    int _ti = __builtin_amdgcn_update_dpp(_si, _si, (ctrl), (rmask), 0xF, false); \
    (s) += __int_as_float(_ti);                                                \
  } while (0)

// one block per pattern p: W2[p,0..31] + bias2[p]
__global__ __launch_bounds__(256) void precompute_kernel(
    const float* __restrict__ conv_w, const float* __restrict__ conv_b,
    const float* __restrict__ keys_w, float* __restrict__ wsf) {
  __shared__ float part[8][32];
  __shared__ float bred[4];
  const int p = blockIdx.x;
  const int t = threadIdx.x;
  const int h = t & 31, g = t >> 5;
  const float* kwp = keys_w + (size_t)p * DIMc;

  float acc = 0.f;
#pragma unroll
  for (int dd = 0; dd < 32; ++dd) {
    int d = g * 32 + dd;
    acc = fmaf(kwp[d], conv_w[d * HIST + h], acc);
  }
  part[g][h] = acc;

  float bp = kwp[t] * conv_b[t];
#pragma unroll
  for (int off = 32; off; off >>= 1) bp += __shfl_down(bp, off);
  if ((t & 63) == 0) bred[t >> 6] = bp;
  __syncthreads();

  if (t < 32) {
    float s = 0.f;
#pragma unroll
    for (int gg = 0; gg < 8; ++gg) s += part[gg][t];
    wsf[(t >> 2) * (NPAT * 4) + p * 4 + (t & 3)] = s;  // float4-friendly
  } else if (t == 32) {
    wsf[NPAT * HIST + p] = (bred[0] + bred[1]) + (bred[2] + bred[3]);
  }
}

__global__ __launch_bounds__(256) void shaper_kernel(
    const float* __restrict__ x, const float* __restrict__ avg_init,
    const float* __restrict__ shapes_w, const float* __restrict__ wsf,
    float* __restrict__ out) {
  __shared__ __align__(16) float xpad[HIST - 1 + Ll + 1];
  __shared__ __align__(16) float scb[2][TC * NPAT];
  __shared__ unsigned int bmw[2][4][64];     // per-chunk win masks, dbuf
  __shared__ unsigned char idx8[Tt];         // winner pattern per step
  __shared__ float shp[WINc * NPAT];

  const int b    = blockIdx.x;
  const int tid  = threadIdx.x;
  const int wid  = tid >> 6;
  const int lane = tid & 63;
  const float* xrow = x + (size_t)b * Ll;

  // ---- stage x (left-padded) + shapes into LDS ----
  if (tid < HIST - 1) xpad[tid] = 0.f;
  {
    const float4* xv4 = (const float4*)xrow;
#pragma unroll
    for (int k = 0; k < 8; ++k) {
      int i4 = k * 256 + tid;
      float4 v = xv4[i4];
      float* dst = xpad + HIST - 1 + i4 * 4;
      dst[0] = v.x; dst[1] = v.y; dst[2] = v.z; dst[3] = v.w;
    }
  }
  for (int i = tid; i < WINc * NPAT; i += 256) shp[i] = shapes_w[i];

  // ---- av0 via DPP-sum butterfly (all waves; validated R5/R8/R10) ----
  float av0;
  {
    float s = avg_init[(size_t)b * NPAT + lane];
    float t = s;
    DPP_ADDF(t, 0xB1, 0xF);
    DPP_ADDF(t, 0x4E, 0xF);
    DPP_ADDF(t, 0x141, 0xF);
    DPP_ADDF(t, 0x140, 0xF);
    DPP_ADDF(t, 0x142, 0xA);
    DPP_ADDF(t, 0x143, 0xC);   // lane63 = total
    float tot = __int_as_float(__builtin_amdgcn_readlane(__float_as_int(t), 63));
    av0 = s - tot * CINV;
  }

  // ---- per-role setup ----
  float4 w2v[8];
  float  b2 = 0.f;
  if (wid > 0) {
    const float4* w2g = (const float4*)wsf;
#pragma unroll
    for (int h4 = 0; h4 < 8; ++h4) w2v[h4] = w2g[h4 * 64 + lane];
    b2 = wsf[NPAT * HIST + lane];
  }
  __syncthreads();

  // fill chunk c: sb[t][p] = (relu6(score) - av0[p]) + tglob/64  (== U_t[p])
  // (bitwise-identical to R12; do not touch the fma order)
  auto fill = [&](int c, float* __restrict__ sb) {
    int base = c * TC;
    for (int tl = wid - 1; tl < TC; tl += 3) {
      int t = base + tl;
      const float4* xw = (const float4*)(xpad + t * WINc);  // 32B-aligned
      float acc = b2;
#pragma unroll
      for (int h4 = 0; h4 < 8; ++h4) {
        float4 xv = xw[h4];
        float4 wv = w2v[h4];
        acc = fmaf(xv.x, wv.x, acc);
        acc = fmaf(xv.y, wv.y, acc);
        acc = fmaf(xv.z, wv.z, acc);
        acc = fmaf(xv.w, wv.w, acc);
      }
      float sc = fminf(fmaxf(acc, 0.f), 6.f);
      sb[tl * NPAT + lane] = (sc - av0) + (float)t * CINV;
    }
  };

  // ---- scan state (wave 0): per-slot win counts, across chunks ----
  float C0 = 0.f, C1 = 0.f, C2 = 0.f, C3 = 0.f;

  // 4 patterns/lane scan: lane l holds patterns 4l..4l+3 (lanes 0-15 live).
  auto scan_chunk = [&](const float* __restrict__ sb, int cidx) {
    const float* myp = sb + 4 * lane;
    float4 ub[4];
    ub[0] = *(const float4*)(myp + 0 * NPAT);
    ub[1] = *(const float4*)(myp + 1 * NPAT);
    ub[2] = *(const float4*)(myp + 2 * NPAT);
    ub[3] = *(const float4*)(myp + 3 * NPAT);
    unsigned int bm0 = 0, bm1 = 0, bm2 = 0, bm3 = 0;
    float v0 = ub[0].x - C0, v1 = ub[0].y - C1;
    float v2 = ub[0].z - C2, v3 = ub[0].w - C3;
#pragma unroll
    for (int i = 0; i < TC; ++i) {
      float4 un = ub[(i + 1) & 3];   // U[i+1] (stale at i=TC-1; unused then)
      float vA0 = un.x - C0, vA1 = un.y - C1;
      float vA2 = un.z - C2, vA3 = un.w - C3;
      float vB0 = vA0 - 1.f, vB1 = vA1 - 1.f;
      float vB2 = vA2 - 1.f, vB3 = vA3 - 1.f;
      if (i + 4 < TC)                 // prefetch U[i+4] into freed slot
        ub[i & 3] = *(const float4*)(myp + (i + 4) * NPAT);
      float g = fmaxf(fmaxf(v0, v1), fmaxf(v2, v3));
      DPP_STAGE(g, 0xB1, 0xF);   // xor1
      DPP_STAGE(g, 0x4E, 0xF);   // xor2
      DPP_STAGE(g, 0x141, 0xF);  // xor4 (row_half_mirror)
      DPP_STAGE(g, 0x140, 0xF);  // xor8 (row_mirror) -> 16-lane max
      bool e0 = (v0 == g), e1 = (v1 == g), e2 = (v2 == g), e3 = (v3 == g);
      unsigned int bit = 1u << i;
      C0 = e0 ? C0 + 1.f : C0;
      C1 = e1 ? C1 + 1.f : C1;
      C2 = e2 ? C2 + 1.f : C2;
      C3 = e3 ? C3 + 1.f : C3;
      bm0 = e0 ? (bm0 | bit) : bm0;
      bm1 = e1 ? (bm1 | bit) : bm1;
      bm2 = e2 ? (bm2 | bit) : bm2;
      bm3 = e3 ? (bm3 | bit) : bm3;
      if (i + 1 < TC) {
        v0 = e0 ? vB0 : vA0;
        v1 = e1 ? vB1 : vA1;
        v2 = e2 ? vB2 : vA2;
        v3 = e3 ? vB3 : vA3;
      }
    }
    bmw[cidx & 1][0][lane] = bm0;
    bmw[cidx & 1][1][lane] = bm1;
    bmw[cidx & 1][2][lane] = bm2;
    bmw[cidx & 1][3][lane] = bm3;
  };

  // batched winner extraction for chunk cc, split across fill waves 1-3
  auto extract = [&](int cc) {
    unsigned int m0 = bmw[cc & 1][0][lane];
    unsigned int m1 = bmw[cc & 1][1][lane];
    unsigned int m2 = bmw[cc & 1][2][lane];
    unsigned int m3 = bmw[cc & 1][3][lane];
    for (int i = wid - 1; i < TC; i += 3) {
      unsigned long long k0 = __ballot(((m0 >> i) & 1u) != 0u) & 0xFFFFull;
      unsigned long long k1 = __ballot(((m1 >> i) & 1u) != 0u) & 0xFFFFull;
      unsigned long long k2 = __ballot(((m2 >> i) & 1u) != 0u) & 0xFFFFull;
      unsigned long long k3 = __ballot(((m3 >> i) & 1u) != 0u) & 0xFFFFull;
      int w = 0;
      if (k0) w = 4 * (int)(__ffsll(k0) - 1) + 0;
      if (k1) w = 4 * (int)(__ffsll(k1) - 1) + 1;
      if (k2) w = 4 * (int)(__ffsll(k2) - 1) + 2;
      if (k3) w = 4 * (int)(__ffsll(k3) - 1) + 3;
      if (lane == 0) idx8[cc * TC + i] = (unsigned char)w;
    }
  };

  // ---- pipeline: wave0 scans chunk c; waves1-3 fill chunk c+1 and
  //      extract winners of chunk c-1 ----
  if (wid > 0) fill(0, scb[0]);
  __syncthreads();

  for (int c = 0; c < NC; ++c) {
    if (wid == 0) {
      scan_chunk(scb[c & 1], c);
    } else {
      if (c + 1 < NC) fill(c + 1, scb[(c + 1) & 1]);
      if (c >= 1) extract(c - 1);
    }
    __syncthreads();
  }
  if (wid > 0) extract(NC - 1);
  __syncthreads();

  // ---- epilogue: out[b,l] = relu(shapes[l&7, idx[l>>3]] - x[b,l]) ----
  float4* outv = (float4*)(out + (size_t)b * Ll);
#pragma unroll
  for (int k = 0; k < 8; ++k) {
    int i4 = k * 256 + tid;
    int l0 = i4 * 4;
    int t  = l0 >> 3;
    int w0 = l0 & 7;
    int p  = (int)idx8[t];
    float4 o;
    o.x = fmaxf(shp[(w0 + 0) * NPAT + p] - xpad[HIST - 1 + l0 + 0], 0.f);
    o.y = fmaxf(shp[(w0 + 1) * NPAT + p] - xpad[HIST - 1 + l0 + 1], 0.f);
    o.z = fmaxf(shp[(w0 + 2) * NPAT + p] - xpad[HIST - 1 + l0 + 2], 0.f);
    o.w = fmaxf(shp[(w0 + 3) * NPAT + p] - xpad[HIST - 1 + l0 + 3], 0.f);
    outv[i4] = o;
  }
}

extern "C" void kernel_launch(void* const* d_in, const int* in_sizes, int n_in,
                              void* d_out, int out_size, void* d_ws, size_t ws_size,
                              hipStream_t stream) {
  const float* x        = (const float*)d_in[0];
  const float* avg_init = (const float*)d_in[1];
  const float* conv_w   = (const float*)d_in[2];
  const float* conv_b   = (const float*)d_in[3];
  const float* keys_w   = (const float*)d_in[4];
  const float* shapes_w = (const float*)d_in[5];
  float* wsf = (float*)d_ws;

  precompute_kernel<<<NPAT, 256, 0, stream>>>(conv_w, conv_b, keys_w, wsf);
  shaper_kernel<<<Bb, 256, 0, stream>>>(x, avg_init, shapes_w, wsf,
                                        (float*)d_out);
}

// Round 4
// 164.321 us; speedup vs baseline: 1.1669x; 1.1669x over previous
//
#include <hip/hip_runtime.h>

// ---------------------------------------------------------------------------
// QuantizedShaper: B=256, L=8192, DIM=256, NPAT=64, HIST=32, WIN=8, T=1024.
//
// R16 = R14 structure (best shaper: 113 us) with a VCC-FREE scan step.
// Evidence R12-R15: per-step cost ~ 16cyc x chain-deps + ~5-6cyc x instrs;
// every variant kept a v_cmp->VCC->v_cndmask round-trip (SGPR-file coupling,
// same family as R12's readlane / R13's ballot chains). R16 replaces the
// compare/select with float-mask arithmetic on the VALU forwarding path:
//   d  = g - v                  (+0 iff winner; distinct floats => d>=2^-149)
//   t1 = d * 2^75; t2 = fmaf(t1, -2^75, 1.0f)   (d=0 -> 1; d>0 -> <= -1)
//   e  = med3(t2, 0, 1)         == (v == gmax) ? 1.0 : 0.0  (incl. +-0 cases)
//   v' = pA - e    (pA = U[i+1]-C_prev; == validated e?vA-1:vA, e in {0,1})
//   C += e;  bm via fmaf(e, 2^i, bmlo/bmhi)  (exact: power-of-2 sums < 2^16)
// 15 instrs/step, chain = 8 cross-lane + 5 plain VALU, zero VCC/SALU.
// Everything else (fill, pipeline, wave-1 batched extraction, epilogue)
// bitwise-identical to R14 (absmax 0.0).
// ---------------------------------------------------------------------------

constexpr int Bb = 256, Ll = 8192, DIMc = 256, NPAT = 64, HIST = 32, WINc = 8;
constexpr int Tt = Ll / WINc;   // 1024
constexpr int TC = 32;          // t-chunk
constexpr int NC = Tt / TC;     // 32 chunks
constexpr float CINV = 1.0f / 64.0f;

#define DPP_STAGE(m, ctrl, rmask)                                              \
  (m) = fmaxf((m), __int_as_float(__builtin_amdgcn_update_dpp(                 \
            __float_as_int(m), __float_as_int(m), (ctrl), (rmask), 0xF, false)))

#define DPP_ADDF(s, ctrl, rmask)                                               \
  do {                                                                         \
    int _si = __float_as_int(s);                                               \
    int _ti = __builtin_amdgcn_update_dpp(_si, _si, (ctrl), (rmask), 0xF, false); \
    (s) += __int_as_float(_ti);                                                \
  } while (0)

#if defined(__has_builtin)
#if __has_builtin(__builtin_amdgcn_permlane16_swap)
#define HAVE_PL16 1
#endif
#if __has_builtin(__builtin_amdgcn_permlane32_swap)
#define HAVE_PL32 1
#endif
#if __has_builtin(__builtin_amdgcn_fmed3f)
#define HAVE_MED3 1
#endif
#endif

__device__ __forceinline__ float clamp01(float t) {
#if defined(HAVE_MED3)
  return __builtin_amdgcn_fmed3f(t, 0.0f, 1.0f);
#else
  return fminf(fmaxf(t, 0.0f), 1.0f);
#endif
}

// 64-lane max, result in ALL lanes, pure VALU (no readlane).
// Validated R13/R14 (absmax 0.0).
__device__ __forceinline__ float wave_max64(float v, int lane) {
  float m = v;
  DPP_STAGE(m, 0xB1, 0xF);   // xor1
  DPP_STAGE(m, 0x4E, 0xF);   // xor2
  DPP_STAGE(m, 0x141, 0xF);  // row_half_mirror -> 8-group max
  DPP_STAGE(m, 0x140, 0xF);  // row_mirror -> 16-row max (row-uniform)
#if defined(HAVE_PL16)
  {
    auto r = __builtin_amdgcn_permlane16_swap(__float_as_int(m),
                                              __float_as_int(m), false, false);
    m = fmaxf(__int_as_float(r[0]), __int_as_float(r[1]));  // 32-half max
  }
#else
  m = fmaxf(m, __int_as_float(
                   __builtin_amdgcn_ds_swizzle(__float_as_int(m), 0x401F)));
#endif
#if defined(HAVE_PL32)
  {
    auto r = __builtin_amdgcn_permlane32_swap(__float_as_int(m),
                                              __float_as_int(m), false, false);
    m = fmaxf(__int_as_float(r[0]), __int_as_float(r[1]));  // global max
  }
#else
  m = fmaxf(m, __int_as_float(__builtin_amdgcn_ds_bpermute(
                   ((lane ^ 32) << 2), __float_as_int(m))));
#endif
  return m;
}

// one block per pattern p: W2[p,0..31] + bias2[p]
__global__ __launch_bounds__(256) void precompute_kernel(
    const float* __restrict__ conv_w, const float* __restrict__ conv_b,
    const float* __restrict__ keys_w, float* __restrict__ wsf) {
  __shared__ float part[8][32];
  __shared__ float bred[4];
  const int p = blockIdx.x;
  const int t = threadIdx.x;
  const int h = t & 31, g = t >> 5;
  const float* kwp = keys_w + (size_t)p * DIMc;

  float acc = 0.f;
#pragma unroll
  for (int dd = 0; dd < 32; ++dd) {
    int d = g * 32 + dd;
    acc = fmaf(kwp[d], conv_w[d * HIST + h], acc);
  }
  part[g][h] = acc;

  float bp = kwp[t] * conv_b[t];
#pragma unroll
  for (int off = 32; off; off >>= 1) bp += __shfl_down(bp, off);
  if ((t & 63) == 0) bred[t >> 6] = bp;
  __syncthreads();

  if (t < 32) {
    float s = 0.f;
#pragma unroll
    for (int gg = 0; gg < 8; ++gg) s += part[gg][t];
    wsf[(t >> 2) * (NPAT * 4) + p * 4 + (t & 3)] = s;  // float4-friendly
  } else if (t == 32) {
    wsf[NPAT * HIST + p] = (bred[0] + bred[1]) + (bred[2] + bred[3]);
  }
}

__global__ __launch_bounds__(256) void shaper_kernel(
    const float* __restrict__ x, const float* __restrict__ avg_init,
    const float* __restrict__ shapes_w, const float* __restrict__ wsf,
    float* __restrict__ out) {
  __shared__ __align__(16) float xpad[HIST - 1 + Ll + 1];
  __shared__ float scb[2][TC * NPAT];
  __shared__ unsigned long long idxp[NC * 4];  // 8 winners per u64
  __shared__ unsigned int bmbuf[2][64];        // per-lane win masks, dbuf
  __shared__ float shp[WINc * NPAT];

  const int b    = blockIdx.x;
  const int tid  = threadIdx.x;
  const int wid  = tid >> 6;
  const int lane = tid & 63;
  const float* xrow = x + (size_t)b * Ll;

  // ---- stage x (left-padded) + shapes into LDS ----
  if (tid < HIST - 1) xpad[tid] = 0.f;
  {
    const float4* xv4 = (const float4*)xrow;
#pragma unroll
    for (int k = 0; k < 8; ++k) {
      int i4 = k * 256 + tid;
      float4 v = xv4[i4];
      float* dst = xpad + HIST - 1 + i4 * 4;
      dst[0] = v.x; dst[1] = v.y; dst[2] = v.z; dst[3] = v.w;
    }
  }
  for (int i = tid; i < WINc * NPAT; i += 256) shp[i] = shapes_w[i];

  // ---- av0 via DPP-sum butterfly (all waves; validated R5/R8/R10) ----
  float av0;
  {
    float s = avg_init[(size_t)b * NPAT + lane];
    float t = s;
    DPP_ADDF(t, 0xB1, 0xF);
    DPP_ADDF(t, 0x4E, 0xF);
    DPP_ADDF(t, 0x141, 0xF);
    DPP_ADDF(t, 0x140, 0xF);
    DPP_ADDF(t, 0x142, 0xA);
    DPP_ADDF(t, 0x143, 0xC);   // lane63 = total
    float tot = __int_as_float(__builtin_amdgcn_readlane(__float_as_int(t), 63));
    av0 = s - tot * CINV;
  }

  // ---- per-role setup ----
  float4 w2v[8];
  float  b2 = 0.f;
  if (wid > 0) {
    const float4* w2g = (const float4*)wsf;
#pragma unroll
    for (int h4 = 0; h4 < 8; ++h4) w2v[h4] = w2g[h4 * 64 + lane];
    b2 = wsf[NPAT * HIST + lane];
  }
  __syncthreads();

  // fill chunk c: sb[t][p] = (relu6(score) - av0[p]) + tglob/64  (== U_t[p])
  auto fill = [&](int c, float* __restrict__ sb) {
    int base = c * TC;
    for (int tl = wid - 1; tl < TC; tl += 3) {
      int t = base + tl;
      const float4* xw = (const float4*)(xpad + t * WINc);  // 32B-aligned
      float acc = b2;
#pragma unroll
      for (int h4 = 0; h4 < 8; ++h4) {
        float4 xv = xw[h4];
        float4 wv = w2v[h4];
        acc = fmaf(xv.x, wv.x, acc);
        acc = fmaf(xv.y, wv.y, acc);
        acc = fmaf(xv.z, wv.z, acc);
        acc = fmaf(xv.w, wv.w, acc);
      }
      float sc = fminf(fmaxf(acc, 0.f), 6.f);
      sb[tl * NPAT + lane] = (sc - av0) + (float)t * CINV;
    }
  };

  // ---- scan state (wave 0): C = win count (starts 0), across chunks ----
  float C = 0.f;
  constexpr float SC75 = 37778931862957161709568.0f;  // 2^75

  // VCC-free scan: per-step state update entirely on the VALU forwarding
  // path (no v_cmp/cndmask, no ballot, no readlane in the loop).
  auto scan_chunk = [&](const float* __restrict__ sb, int cidx) {
    float U[TC];
#pragma unroll
    for (int i = 0; i < TC; ++i) U[i] = sb[i * NPAT + lane];
    float bmlo = 0.f, bmhi = 0.f;
    float v  = U[0] - C;
    float pA = U[1] - C;     // U[i+1] - C_{i-1} rolling
#pragma unroll
    for (int i = 0; i < TC; ++i) {
      float g  = wave_max64(v, lane);
      float d  = g - v;                      // +0 iff winner (exact)
      float t1 = d * SC75;
      float t2 = __builtin_fmaf(t1, -SC75, 1.0f);  // 1 - d*2^150
      float e  = clamp01(t2);                // == (v==g) ? 1 : 0
      C += e;                                // integer-exact
      if (i < 16) bmlo = __builtin_fmaf(e, (float)(1u << i), bmlo);
      else        bmhi = __builtin_fmaf(e, (float)(1u << (i - 16)), bmhi);
      if (i + 1 < TC) {
        v = pA - e;                          // == e ? vA-1 : vA (bitwise)
        if (i + 2 < TC) pA = U[i + 2] - C;   // for next step
      }
    }
    unsigned int bm = (unsigned int)bmlo | ((unsigned int)bmhi << 16);
    bmbuf[cidx & 1][lane] = bm;
  };

  // batched winner extraction for chunk cc (any single wave; uses ballot)
  auto extract = [&](int cc) {
    unsigned int bmv = bmbuf[cc & 1][lane];
    unsigned long long pk0 = 0, pk1 = 0, pk2 = 0, pk3 = 0;
#pragma unroll
    for (int i = 0; i < TC; ++i) {
      unsigned long long mk = __ballot(((bmv >> i) & 1u) != 0u);
      unsigned long long w = (unsigned long long)(__ffsll(mk) - 1);
      if (i < 8)       pk0 |= w << (8 * (i & 7));
      else if (i < 16) pk1 |= w << (8 * (i & 7));
      else if (i < 24) pk2 |= w << (8 * (i & 7));
      else             pk3 |= w << (8 * (i & 7));
    }
    if (lane == 0) {
      idxp[cc * 4 + 0] = pk0;
      idxp[cc * 4 + 1] = pk1;
      idxp[cc * 4 + 2] = pk2;
      idxp[cc * 4 + 3] = pk3;
    }
  };

  // ---- pipeline: wave0 scans chunk c; waves1-3 fill chunk c+1;
  //      wave1 additionally extracts winners of chunk c-1 ----
  if (wid > 0) fill(0, scb[0]);
  __syncthreads();

  for (int c = 0; c < NC; ++c) {
    if (wid == 0) {
      scan_chunk(scb[c & 1], c);
    } else {
      if (c + 1 < NC) fill(c + 1, scb[(c + 1) & 1]);
      if (wid == 1 && c >= 1) extract(c - 1);
    }
    __syncthreads();
  }
  if (wid == 0) extract(NC - 1);
  __syncthreads();

  // ---- epilogue: out[b,l] = relu(shapes[l&7, idx[l>>3]] - x[b,l]) ----
  float4* outv = (float4*)(out + (size_t)b * Ll);
#pragma unroll
  for (int k = 0; k < 8; ++k) {
    int i4 = k * 256 + tid;
    int l0 = i4 * 4;
    int t  = l0 >> 3;
    int w0 = l0 & 7;
    int p  = (int)((idxp[t >> 3] >> (8 * (t & 7))) & 63ull);
    float4 o;
    o.x = fmaxf(shp[(w0 + 0) * NPAT + p] - xpad[HIST - 1 + l0 + 0], 0.f);
    o.y = fmaxf(shp[(w0 + 1) * NPAT + p] - xpad[HIST - 1 + l0 + 1], 0.f);
    o.z = fmaxf(shp[(w0 + 2) * NPAT + p] - xpad[HIST - 1 + l0 + 2], 0.f);
    o.w = fmaxf(shp[(w0 + 3) * NPAT + p] - xpad[HIST - 1 + l0 + 3], 0.f);
    outv[i4] = o;
  }
}

extern "C" void kernel_launch(void* const* d_in, const int* in_sizes, int n_in,
                              void* d_out, int out_size, void* d_ws, size_t ws_size,
                              hipStream_t stream) {
  const float* x        = (const float*)d_in[0];
  const float* avg_init = (const float*)d_in[1];
  const float* conv_w   = (const float*)d_in[2];
  const float* conv_b   = (const float*)d_in[3];
  const float* keys_w   = (const float*)d_in[4];
  const float* shapes_w = (const float*)d_in[5];
  float* wsf = (float*)d_ws;

  precompute_kernel<<<NPAT, 256, 0, stream>>>(conv_w, conv_b, keys_w, wsf);
  shaper_kernel<<<Bb, 256, 0, stream>>>(x, avg_init, shapes_w, wsf,
                                        (float*)d_out);
}